// Round 2
// baseline (534.956 us; speedup 1.0000x reference)
//
#include <hip/hip_runtime.h>
#include <hip/hip_bf16.h>

// Problem constants
#define N_  4
#define C_  256
#define K_  16
#define T_  16
#define H_  56
#define W_  56
#define HW_ (H_ * W_)          // 3136
#define THW_ (T_ * HW_)        // 50176
#define TP_ 8
#define HP_ 28
#define WP_ 28
#define PP_ (HP_ * WP_)        // 784
#define CB_ 16                 // channels per thread in box kernel

// ---------------------------------------------------------------------------
// Kernel 1: emap[n,t,h,w] = exp( max_k( sum_c w[n,k,c]*vw[n,c,t,h,w] ) / 16 )
// Block = 256 threads = 4 waves. Each wave owns a 64-channel quarter and the
// block's 128 spatial positions (2 per lane, float2 loads -> 512B/wave/instr).
// Partial per-k dots combined across waves via LDS, then max/exp/store.
// w is read directly from global with wave-uniform addresses (L1 broadcast).
// ---------------------------------------------------------------------------
__global__ __launch_bounds__(256) void emap_kernel(const float* __restrict__ vw,
                                                   const float* __restrict__ w,
                                                   float* __restrict__ emap) {
    __shared__ float part[K_][4][128];      // 32 KB
    const int tid  = threadIdx.x;
    const int wave = tid >> 6;
    const int lane = tid & 63;
    const int bpn  = THW_ / 128;            // 392 blocks per n
    const int n    = blockIdx.x / bpn;
    const int s0   = (blockIdx.x % bpn) * 128;
    const int s    = s0 + lane * 2;

    const float* vbase = vw + (long)(n * C_ + wave * 64) * THW_ + s;
    const float* wn    = w + n * (K_ * C_) + wave * 64;

    float a0[K_], a1[K_];
#pragma unroll
    for (int k = 0; k < K_; ++k) { a0[k] = 0.f; a1[k] = 0.f; }

    for (int c = 0; c < 64; c += 4) {
        float2 v0 = *(const float2*)(vbase + (long)(c + 0) * THW_);
        float2 v1 = *(const float2*)(vbase + (long)(c + 1) * THW_);
        float2 v2 = *(const float2*)(vbase + (long)(c + 2) * THW_);
        float2 v3 = *(const float2*)(vbase + (long)(c + 3) * THW_);
#pragma unroll
        for (int k = 0; k < K_; ++k) {
            const float4 wk = *(const float4*)&wn[k * C_ + c];   // wave-uniform
            a0[k] += wk.x * v0.x + wk.y * v1.x + wk.z * v2.x + wk.w * v3.x;
            a1[k] += wk.x * v0.y + wk.y * v1.y + wk.z * v2.y + wk.w * v3.y;
        }
    }

    // write per-wave partials
#pragma unroll
    for (int k = 0; k < K_; ++k) {
        *(float2*)&part[k][wave][lane * 2] = make_float2(a0[k], a1[k]);
    }
    __syncthreads();

    // reduce: tid -> pos = tid>>1 in [0,128), kh = tid&1 picks 8 of 16 k's
    const int pos = tid >> 1, kh = tid & 1;
    float m = -1e30f;
#pragma unroll
    for (int j = 0; j < 8; ++j) {
        const int k = kh * 8 + j;
        const float sum = part[k][0][pos] + part[k][1][pos]
                        + part[k][2][pos] + part[k][3][pos];
        m = fmaxf(m, sum);
    }
    m = fmaxf(m, __shfl_xor(m, 1));
    if (kh == 0) emap[(long)n * THW_ + s0 + pos] = expf(m * 0.0625f);
}

// ---------------------------------------------------------------------------
// Kernel 2: out = boxsum3x3x3(vw*emap) / boxsum3x3x3(emap), stride 2, pad 1.
// No LDS, no barriers. One thread per output position; loops CB_ channels.
// The 27 emap taps are loaded ONCE into registers (denominator = their sum),
// then reused for every channel. OOB taps: clamp address, zero e[i].
// ---------------------------------------------------------------------------
__global__ __launch_bounds__(256) void box_kernel(const float* __restrict__ vw,
                                                  const float* __restrict__ emap,
                                                  float* __restrict__ out) {
    const int gid = blockIdx.x * 256 + threadIdx.x;    // [0, 25088)
    const int n   = gid / (TP_ * PP_);
    const int r   = gid % (TP_ * PP_);
    const int tp  = r / PP_;
    const int p   = r % PP_;
    const int hp  = p / WP_, wp = p % WP_;
    const int t0  = 2 * tp - 1, h0 = 2 * hp - 1, w0 = 2 * wp - 1;
    const int c0  = blockIdx.y * CB_;

    const float* ebase = emap + (long)n * THW_;

    float e[27];
    int   off[27];
    float den = 0.f;
#pragma unroll
    for (int dt = 0; dt < 3; ++dt) {
        const int tt = t0 + dt;
        const bool tvld = (tt >= 0);            // tt <= 15 always
        const int tc = tvld ? tt : 0;
#pragma unroll
        for (int dh = 0; dh < 3; ++dh) {
            const int h = h0 + dh;
            const bool hvld = (h >= 0);         // h <= 55 always
            const int hc = hvld ? h : 0;
#pragma unroll
            for (int dw = 0; dw < 3; ++dw) {
                const int w = w0 + dw;
                const bool wvld = (w >= 0);     // w <= 55 always
                const int wc = wvld ? w : 0;
                const int i = (dt * 3 + dh) * 3 + dw;
                off[i] = tc * HW_ + hc * W_ + wc;
                float ev = ebase[off[i]];
                ev = (tvld && hvld && wvld) ? ev : 0.f;
                e[i] = ev;
                den += ev;
            }
        }
    }
    const float rden = 1.0f / den;

    const float* vb = vw + ((long)n * C_ + c0) * THW_;
    float* ob = out + (((long)n * C_ + c0) * TP_ + tp) * PP_ + p;

    for (int c = 0; c < CB_; ++c) {
        const float* vc = vb + (long)c * THW_;
        float n0 = 0.f, n1 = 0.f, n2 = 0.f;
#pragma unroll
        for (int i = 0; i < 27; i += 3) {
            n0 += vc[off[i + 0]] * e[i + 0];
            n1 += vc[off[i + 1]] * e[i + 1];
            n2 += vc[off[i + 2]] * e[i + 2];
        }
        ob[(long)c * (TP_ * PP_)] = (n0 + n1 + n2) * rden;
    }
}

extern "C" void kernel_launch(void* const* d_in, const int* in_sizes, int n_in,
                              void* d_out, int out_size, void* d_ws, size_t ws_size,
                              hipStream_t stream) {
    const float* vw = (const float*)d_in[0];
    const float* w  = (const float*)d_in[1];
    float* out  = (float*)d_out;
    float* emap = (float*)d_ws;     // N*T*H*W*4 = 802816 bytes

    // Kernel 1: 4 n * 392 = 1568 blocks (6.1 waves/SIMD)
    emap_kernel<<<1568, 256, 0, stream>>>(vw, w, emap);

    // Kernel 2: grid (25088/256 = 98 position-blocks, 16 c-chunks)
    box_kernel<<<dim3(98, C_ / CB_), 256, 0, stream>>>(vw, emap, out);
}

// Round 4
// 343.872 us; speedup vs baseline: 1.5557x; 1.5557x over previous
//
#include <hip/hip_runtime.h>
#include <hip/hip_bf16.h>

// Problem constants
#define N_  4
#define C_  256
#define K_  16
#define T_  16
#define H_  56
#define W_  56
#define HW_ (H_ * W_)          // 3136
#define THW_ (T_ * HW_)        // 50176
#define TP_ 8
#define HP_ 28
#define WP_ 28
#define PP_ (HP_ * WP_)        // 784

// ---------------------------------------------------------------------------
// Kernel 1: emap[n,t,h,w] = exp( max_k( sum_c w[n,k,c]*vw[n,c,t,h,w] ) / 16 )
// Block = 256 thr = 4 waves, covers 256 consecutive spatial positions.
// Wave wv owns channel quarter [wv*64, wv*64+64); each lane owns 4 positions
// (float4 loads, 16B/lane). w[n] staged TRANSPOSED in LDS (wt[c][k]) so the
// inner loop reads it with uniform-address broadcast ds_read_b128 (no global
// loads, no conflicts). Partials combined across waves via LDS in two
// 8-k chunks (32 KB), max/exp/store by one thread per position.
// ---------------------------------------------------------------------------
__global__ __launch_bounds__(256) void emap_kernel(const float* __restrict__ vw,
                                                   const float* __restrict__ w,
                                                   float* __restrict__ emap) {
    __shared__ float wt[C_ * K_];           // 16 KB, wt[c*16+k] = w[n][k][c]
    __shared__ float part[8][4][256];       // 32 KB, one 8-k chunk of partials

    const int tid  = threadIdx.x;
    const int wv   = tid >> 6;
    const int lane = tid & 63;
    const int bpn  = THW_ / 256;            // 196 blocks per n
    const int n    = blockIdx.x / bpn;
    const int s0   = (blockIdx.x % bpn) * 256;

    // stage w transposed (reads coalesced per k; done once)
    const float* wn = w + n * (K_ * C_);
#pragma unroll
    for (int k = 0; k < K_; ++k) wt[tid * K_ + k] = wn[k * C_ + tid];
    __syncthreads();

    const float* vbase = vw + (long)(n * C_ + wv * 64) * THW_ + s0 + (lane << 2);

    float a[K_][4];
#pragma unroll
    for (int k = 0; k < K_; ++k)
#pragma unroll
        for (int p = 0; p < 4; ++p) a[k][p] = 0.f;

#pragma unroll 2
    for (int g = 0; g < 16; ++g) {
        float4 vv[4];
#pragma unroll
        for (int j = 0; j < 4; ++j)
            vv[j] = *(const float4*)(vbase + (long)(g * 4 + j) * THW_);
#pragma unroll
        for (int j = 0; j < 4; ++j) {
            const int c = wv * 64 + g * 4 + j;
#pragma unroll
            for (int kk = 0; kk < 4; ++kk) {
                const float4 wk = *(const float4*)&wt[c * K_ + kk * 4];
#define FMA4(Q, WC) \
                a[kk*4+Q][0] += (WC) * vv[j].x; a[kk*4+Q][1] += (WC) * vv[j].y; \
                a[kk*4+Q][2] += (WC) * vv[j].z; a[kk*4+Q][3] += (WC) * vv[j].w;
                FMA4(0, wk.x) FMA4(1, wk.y) FMA4(2, wk.z) FMA4(3, wk.w)
#undef FMA4
            }
        }
    }

    // two 8-k chunks: write partials, sync, reduce, sync
    float m = -3.4e38f;
#pragma unroll
    for (int kc = 0; kc < 2; ++kc) {
#pragma unroll
        for (int kq = 0; kq < 8; ++kq) {
            *(float4*)&part[kq][wv][lane * 4] =
                make_float4(a[kc*8+kq][0], a[kc*8+kq][1], a[kc*8+kq][2], a[kc*8+kq][3]);
        }
        __syncthreads();
        float ml = -3.4e38f;
#pragma unroll
        for (int kq = 0; kq < 8; ++kq) {
            const float s = part[kq][0][tid] + part[kq][1][tid]
                          + part[kq][2][tid] + part[kq][3][tid];
            ml = fmaxf(ml, s);
        }
        m = fmaxf(m, ml);
        __syncthreads();
    }

    emap[(long)n * THW_ + s0 + tid] = expf(m * 0.0625f);
}

// ---------------------------------------------------------------------------
// Kernel 2: rden[n,tp,h',w'] = 1 / boxsum3x3x3(emap). One thread per output
// position; 27 gathered taps (emap is 0.8 MB -> L2/L3 resident). Tiny.
// ---------------------------------------------------------------------------
__global__ __launch_bounds__(256) void rden_kernel(const float* __restrict__ emap,
                                                   float* __restrict__ rden) {
    const int gid = blockIdx.x * 256 + threadIdx.x;   // [0, 25088)
    const int n   = gid / (TP_ * PP_);
    const int r   = gid % (TP_ * PP_);
    const int tp  = r / PP_;
    const int p   = r % PP_;
    const int hp  = p / WP_, wp = p % WP_;
    const int t0  = 2 * tp - 1, h0 = 2 * hp - 1, w0 = 2 * wp - 1;
    const float* eb = emap + (long)n * THW_;

    float den = 0.f;
#pragma unroll
    for (int dt = 0; dt < 3; ++dt) {
        const int tt = t0 + dt;
        const bool tv = (tt >= 0);
        const int tc = tv ? tt : 0;
#pragma unroll
        for (int dh = 0; dh < 3; ++dh) {
            const int h = h0 + dh;
            const bool hv = tv && (h >= 0);
            const int hc = (h >= 0) ? h : 0;
#pragma unroll
            for (int dw = 0; dw < 3; ++dw) {
                const int w = w0 + dw;
                const bool v = hv && (w >= 0);
                const int wc = (w >= 0) ? w : 0;
                const float ev = eb[tc * HW_ + hc * W_ + wc];
                den += v ? ev : 0.f;
            }
        }
    }
    rden[gid] = 1.0f / den;
}

// ---------------------------------------------------------------------------
// Kernel 3: block = (c, t', n). Stages p = vw*emap for the 3 input t-slices
// into LDS (37.6 KB, coalesced float4 in, b128 LDS writes), plus the rden
// tile (3.1 KB). Each output = sum of 27 LDS taps (stride-2 lanes = 2-way
// bank aliasing = free) * rden.
// ---------------------------------------------------------------------------
__global__ __launch_bounds__(256) void box_kernel(const float* __restrict__ vw,
                                                  const float* __restrict__ emap,
                                                  const float* __restrict__ rden,
                                                  float* __restrict__ out) {
    __shared__ float sp[3][HW_];     // 37632 B
    __shared__ float sr[PP_];        // 3136 B

    const int tid = threadIdx.x;
    const int c   = blockIdx.x;
    const int tp  = blockIdx.y;
    const int n   = blockIdx.z;
    const int t0  = 2 * tp - 1;

    const float* eb = emap + (long)n * THW_;
    const float* vb = vw + (long)(n * C_ + c) * THW_;

    // stage product tile
#pragma unroll
    for (int sl = 0; sl < 3; ++sl) {
        const int tt = t0 + sl;
        if (tt >= 0) {                       // tt <= 15 always
            const float4* vs = (const float4*)(vb + tt * HW_);
            const float4* es = (const float4*)(eb + tt * HW_);
            for (int i = tid; i < HW_ / 4; i += 256) {
                const float4 v = vs[i], e = es[i];
                *(float4*)&sp[sl][i * 4] =
                    make_float4(v.x * e.x, v.y * e.y, v.z * e.z, v.w * e.w);
            }
        } else {
            for (int i = tid; i < HW_ / 4; i += 256)
                *(float4*)&sp[sl][i * 4] = make_float4(0.f, 0.f, 0.f, 0.f);
        }
    }
    const float* rt = rden + (n * TP_ + tp) * PP_;
    for (int i = tid; i < PP_; i += 256) sr[i] = rt[i];
    __syncthreads();

    float* ob = out + (((long)(n * C_ + c)) * TP_ + tp) * PP_;
    for (int p = tid; p < PP_; p += 256) {
        const int hp = p / WP_, wp = p % WP_;
        const int h0 = 2 * hp - 1, w0 = 2 * wp - 1;
        float num = 0.f;
#pragma unroll
        for (int dh = 0; dh < 3; ++dh) {
            const int h = h0 + dh;
            const bool hv = (h >= 0);
            const int hc = hv ? h : 0;
#pragma unroll
            for (int dw = 0; dw < 3; ++dw) {
                const int w = w0 + dw;
                const bool v = hv && (w >= 0);
                const int wc = (w >= 0) ? w : 0;
                const int o = hc * W_ + wc;
                const float s3 = sp[0][o] + sp[1][o] + sp[2][o];
                num += v ? s3 : 0.f;
            }
        }
        ob[p] = num * sr[p];
    }
}

extern "C" void kernel_launch(void* const* d_in, const int* in_sizes, int n_in,
                              void* d_out, int out_size, void* d_ws, size_t ws_size,
                              hipStream_t stream) {
    const float* vw = (const float*)d_in[0];
    const float* w  = (const float*)d_in[1];
    float* out  = (float*)d_out;
    float* emap = (float*)d_ws;                 // 200704 floats * 4n = 802816 B
    float* rden = emap + (long)N_ * THW_;       // 25088 floats = 100352 B

    // Kernel 1: 784 blocks (196 per n)
    emap_kernel<<<784, 256, 0, stream>>>(vw, w, emap);

    // Kernel 2: 98 blocks
    rden_kernel<<<98, 256, 0, stream>>>(emap, rden);

    // Kernel 3: grid (c=256, tp=8, n=4) = 8192 blocks
    box_kernel<<<dim3(C_, TP_, N_), 256, 0, stream>>>(vw, emap, rden, out);
}